// Round 8
// baseline (60.228 us; speedup 1.0000x reference)
//
#include <hip/hip_runtime.h>

// ---------------------------------------------------------------------------
// out[b,o] = sum_{f,p} x0[b,f]*x[b,p]*W[o,f,p] + bias[o]
//   == GEMM C[4096,256] = A[4096,16384] * W^T,  A[b,f*128+p] = x0[b,f]*x[b,p]
// R8: barrier-free K-loop, register-resident A, B streamed L2->regs.
// R1/R3/R6/R7 (all LDS-staged, barrier-per-step) cluster at 48-88us: m233's
// lockstep stall (~72% of step time) dominates regardless of staging flavor.
// R4/R5 (global-streamed B) failed only because 512-thr blocks cap VGPR at
// 128 -> xr demoted (VGPR=84/96). Fix = R7's block shape: 256 thr, 4 waves
// (2m x 2n), __launch_bounds__(256,2) -> 256-reg budget; acc(64)+xr(64)+
// bwA/bwB(64)+addr fits (~220). K-loop: 8 coalesced global_load_dwordx4
// (WT fragment-ordered, 1KB/wave each, XCD-L2-resident via sk=bid&7) +
// 32 MFMA per step, named double buffers, NO barriers / NO asm / NO LDS
// except a 2-dword broadcast x0 read per 2 steps. Compiler owns vmcnt
// scheduling (G7). Split-K=8 via f32 atomics onto bias-initialized out.
// ---------------------------------------------------------------------------

typedef _Float16 f16x8 __attribute__((ext_vector_type(8)));
typedef float    f32x4 __attribute__((ext_vector_type(4)));

#define WS_WT_OFF 0
#define WS_XF_OFF 8388608
#define WS_NEEDED 9437184

__device__ __forceinline__ void gl_lds16(const void* g, void* l) {
  __builtin_amdgcn_global_load_lds(
      (const __attribute__((address_space(1))) void*)g,
      (__attribute__((address_space(3))) void*)l, 16, 0, 0);
}

// ------------------------------ prep kernel --------------------------------
// [0,524288): W f32->f16 into MFMA-fragment order:
//   WT byte addr = (kstep*16 + o/16)*2048 + ((k%64)/8)*256 + (o%16)*16 + (k%8)*2
//   -> a wave's B-frag (16 o x 32 k) = 1 KB contiguous.
// [524288,589824): x f32->f16 + XOR-seg swizzle (reader-matched).
// [589824,851968): out = bias (float4 groups).
__global__ __launch_bounds__(256) void prep_kernel(
    const float* __restrict__ x, const float* __restrict__ W,
    const float* __restrict__ bias, char* __restrict__ WT,
    _Float16* __restrict__ Xf, float* __restrict__ out)
{
  int i = blockIdx.x * 256 + threadIdx.x;
  if (i < 524288) {
    int o = i >> 11, k8 = i & 2047;        // k8: 8-elem k-granule within row o
    const float* s = W + ((size_t)o << 14) + ((size_t)k8 << 3);
    f16x8 h;
#pragma unroll
    for (int e = 0; e < 8; ++e) h[e] = (_Float16)s[e];
    int sg  = k8 >> 3;                     // global k-step 0..255
    int seg = k8 & 7;
    char* dst = WT + ((size_t)(sg * 16 + (o >> 4))) * 2048 + seg * 256 + (o & 15) * 16;
    *(f16x8*)dst = h;
  } else if (i < 589824) {
    int j = i - 524288;
    int r = j >> 4, seg = j & 15;
    const float* s = x + r * 128 + seg * 8;
    f16x8 h;
#pragma unroll
    for (int e = 0; e < 8; ++e) h[e] = (_Float16)s[e];
    int segp = seg ^ (r & 7);
    *(f16x8*)(Xf + r * 128 + segp * 8) = h;
  } else {
    int j = i - 589824;                    // float4 idx into out[4096][256]
    int c = (j * 4) & 255;
    ((float4*)out)[j] = *(const float4*)(bias + c);
  }
}

// ------------------------------ GEMM kernel --------------------------------
__global__ __launch_bounds__(256, 2) void gemm_kernel(
    const char* __restrict__ WT, const _Float16* __restrict__ Xf,
    const float* __restrict__ x0, float* __restrict__ out)
{
  __shared__ __align__(16) char x_s[32768];   // x tile [128 r][128 p] f16 swz
  __shared__ float x0t[2048];                 // x0^T [16 f][128 r] f32

  const int bid = blockIdx.x;
  const int mb  = bid >> 4;          // 0..31 : 128-row block
  const int nb  = (bid >> 3) & 1;    // 0..1  : 128-o half
  const int sk  = bid & 7;           // 0..7  : split-K chunk -> XCD-resident

  const int t   = threadIdx.x;
  const int l   = t & 63;
  const int wv  = t >> 6;
  const int wm  = wv >> 1;           // 0..1 : 64-row half
  const int wn  = wv & 1;            // 0..1 : 64-o half
  const int lr  = l & 15;
  const int lg  = l >> 4;
  const int swz = lr & 7;

  // ---- prologue: stage x tile; x0 slice -> regs ----
  const char* XfB = (const char*)Xf + (size_t)mb * 32768;
#pragma unroll
  for (int i = 0; i < 8; ++i)
    gl_lds16(XfB + i * 4096 + t * 16, x_s + i * 4096 + t * 16);

  const int r0 = t >> 1, hf = t & 1;
  const float* x0s = x0 + (size_t)(mb * 128 + r0) * 128 + sk * 16 + hf * 8;
  const float4 xa = *(const float4*)(x0s);
  const float4 xb = *(const float4*)(x0s + 4);
  __syncthreads();                            // x_s ready

  x0t[(hf * 8 + 0) * 128 + r0] = xa.x;
  x0t[(hf * 8 + 1) * 128 + r0] = xa.y;
  x0t[(hf * 8 + 2) * 128 + r0] = xa.z;
  x0t[(hf * 8 + 3) * 128 + r0] = xa.w;
  x0t[(hf * 8 + 4) * 128 + r0] = xb.x;
  x0t[(hf * 8 + 5) * 128 + r0] = xb.y;
  x0t[(hf * 8 + 6) * 128 + r0] = xb.z;
  x0t[(hf * 8 + 7) * 128 + r0] = xb.w;

  // x slice -> registers (once; all indices static)
  f16x8 xr[4][2][2];
  const int xrb = (wm * 64 + lr) * 256;
#pragma unroll
  for (int m = 0; m < 4; ++m)
#pragma unroll
    for (int h = 0; h < 2; ++h)
#pragma unroll
      for (int tt = 0; tt < 2; ++tt)
        xr[m][h][tt] = *(const f16x8*)(x_s + xrb + m * 4096 +
                                       (((h * 8 + tt * 4 + lg) ^ swz) << 4));
  __syncthreads();                            // x0t visible to all waves
  // (no barriers from here on)

  // per-lane W stream pointer: kstep base sk*32, o-group nb*8 + wn*4
  const char* wt = WT + ((size_t)(sk * 32) * 16 + nb * 8 + wn * 4) * 2048 + l * 16;
  const int x0i = wm * 64 + lr;

  f32x4 acc[4][4] = {};
  f16x8 bwA[4][2], bwB[4][2];
  _Float16 sh[4];

  // prime: step 0 -> bwA
#pragma unroll
  for (int nI = 0; nI < 4; ++nI)
#pragma unroll
    for (int tt = 0; tt < 2; ++tt)
      bwA[nI][tt] = *(const f16x8*)(wt + nI * 2048 + tt * 1024);

#define MFMA_STEP(BW, PH) \
  _Pragma("unroll") \
  for (int m = 0; m < 4; ++m) { \
    _Pragma("unroll") \
    for (int tt = 0; tt < 2; ++tt) { \
      f16x8 av = xr[m][PH][tt] * sh[m]; \
      _Pragma("unroll") \
      for (int nI = 0; nI < 4; ++nI) \
        acc[m][nI] = __builtin_amdgcn_mfma_f32_16x16x32_f16( \
            av, BW[nI][tt], acc[m][nI], 0, 0, 0); \
    } \
  }

  for (int s = 0; s < 32; s += 2) {
    // prefetch step s+1 (same f, ph=1) into bwB
    const char* wt1 = wt + 32768;
#pragma unroll
    for (int nI = 0; nI < 4; ++nI)
#pragma unroll
      for (int tt = 0; tt < 2; ++tt)
        bwB[nI][tt] = *(const f16x8*)(wt1 + nI * 2048 + tt * 1024);

#pragma unroll
    for (int m = 0; m < 4; ++m)
      sh[m] = (_Float16)x0t[(s >> 1) * 128 + x0i + m * 16];

    MFMA_STEP(bwA, 0)

    // prefetch step s+2 into bwA (final iter overshoots into Xf region of
    // ws — valid memory, values never consumed)
    const char* wt2 = wt + 65536;
#pragma unroll
    for (int nI = 0; nI < 4; ++nI)
#pragma unroll
      for (int tt = 0; tt < 2; ++tt)
        bwA[nI][tt] = *(const f16x8*)(wt2 + nI * 2048 + tt * 1024);

    MFMA_STEP(bwB, 1)

    wt += 65536;
  }
#undef MFMA_STEP

  // ---- epilogue: split-K accumulate (out pre-initialized to bias) ----
  // C/D layout: col = lane&15, row = (lane>>4)*4 + reg
  float* op = out + (size_t)(mb * 128 + wm * 64 + lg * 4) * 256 +
              nb * 128 + wn * 64 + lr;
#pragma unroll
  for (int m = 0; m < 4; ++m)
#pragma unroll
    for (int nI = 0; nI < 4; ++nI)
#pragma unroll
      for (int r = 0; r < 4; ++r)
        unsafeAtomicAdd(op + (size_t)(m * 16 + r) * 256 + nI * 16,
                        acc[m][nI][r]);
}

// --------------------------- fallback (no ws) ------------------------------
__global__ __launch_bounds__(256) void naive_kernel(
    const float* __restrict__ x0, const float* __restrict__ x,
    const float* __restrict__ W, const float* __restrict__ bias,
    float* __restrict__ out)
{
  __shared__ float x0_s[16][128];
  __shared__ float x_s[16][128];
  const int tid = threadIdx.x;
  const int b0  = blockIdx.x * 16;
  for (int i = tid; i < 16 * 128; i += 256) {
    int bb = i >> 7, c = i & 127;
    x0_s[bb][c] = x0[(size_t)(b0 + bb) * 128 + c];
    x_s[bb][c]  = x[(size_t)(b0 + bb) * 128 + c];
  }
  __syncthreads();
  const int lane = tid & 63, wv = tid >> 6;
  for (int o = wv; o < 256; o += 4) {
    float acc[16];
#pragma unroll
    for (int bb = 0; bb < 16; ++bb) acc[bb] = 0.f;
    for (int it = 0; it < 256; ++it) {
      int k = it * 64 + lane;
      float wval = W[(size_t)o * 16384 + k];
      int f = k >> 7, p = k & 127;
#pragma unroll
      for (int bb = 0; bb < 16; ++bb)
        acc[bb] += wval * (x0_s[bb][f] * x_s[bb][p]);
    }
#pragma unroll
    for (int bb = 0; bb < 16; ++bb) {
      float v = acc[bb];
      for (int off = 32; off; off >>= 1) v += __shfl_down(v, off);
      if (lane == 0) out[(size_t)(b0 + bb) * 256 + o] = v + bias[o];
    }
  }
}

// ------------------------------- launcher ----------------------------------
extern "C" void kernel_launch(void* const* d_in, const int* in_sizes, int n_in,
                              void* d_out, int out_size, void* d_ws,
                              size_t ws_size, hipStream_t stream)
{
  const float* x0   = (const float*)d_in[0];
  const float* x    = (const float*)d_in[1];
  const float* W    = (const float*)d_in[2];
  const float* bias = (const float*)d_in[3];
  float* out = (float*)d_out;

  if (ws_size >= (size_t)WS_NEEDED) {
    char*     WT = (char*)d_ws + WS_WT_OFF;
    _Float16* Xf = (_Float16*)((char*)d_ws + WS_XF_OFF);
    prep_kernel<<<3328, 256, 0, stream>>>(x, W, bias, WT, Xf, out);
    gemm_kernel<<<512, 256, 0, stream>>>(WT, Xf, x0, out);
  } else {
    naive_kernel<<<256, 256, 0, stream>>>(x0, x, W, bias, out);
  }
}

// Round 9
// 60.081 us; speedup vs baseline: 1.0024x; 1.0024x over previous
//
#include <hip/hip_runtime.h>

// ---------------------------------------------------------------------------
// out[b,o] = sum_{f,p} x0[b,f]*x[b,p]*W[o,f,p] + bias[o]
//   == GEMM C[4096,256] = A[4096,16384] * W^T,  A[b,f*128+p] = x0[b,f]*x[b,p]
// R9 = R8 + register pinning. R8's VGPR_Count=84 proved the allocator
// rematerialized the A-slice (xr) from LDS inside the K-loop (occupancy
// heuristic), making it R7-with-higher-latency-B. Fix: after the one-time
// xr load, asm volatile("" : "+v"(frag)) pins each of the 16 fragments —
// an asm-defined value can't be rematerialized, so xr stays in VGPRs.
// Budget: xr 64 + bwA/bwB 64 + acc 64 (AGPR) + misc ~210 <= 256
// (__launch_bounds__(256,2), 2 waves/SIMD). K-loop: 8 coalesced
// global_load_dwordx4 of fragment-ordered W (XCD-L2-resident, sk=bid&7) +
// 32 MFMA per step, named double buffers, no barriers/LDS/asm-waits in loop.
// Split-K=8 via f32 atomics onto bias-initialized out.
// ---------------------------------------------------------------------------

typedef _Float16 f16x8 __attribute__((ext_vector_type(8)));
typedef float    f32x4 __attribute__((ext_vector_type(4)));

#define WS_WT_OFF 0
#define WS_XF_OFF 8388608
#define WS_NEEDED 9437184

__device__ __forceinline__ void gl_lds16(const void* g, void* l) {
  __builtin_amdgcn_global_load_lds(
      (const __attribute__((address_space(1))) void*)g,
      (__attribute__((address_space(3))) void*)l, 16, 0, 0);
}

// ------------------------------ prep kernel --------------------------------
// [0,524288): W f32->f16 into MFMA-fragment order:
//   WT byte addr = (kstep*16 + o/16)*2048 + ((k%64)/8)*256 + (o%16)*16 + (k%8)*2
//   -> a wave's B-frag (16 o x 32 k) = 1 KB contiguous.
// [524288,589824): x f32->f16 + XOR-seg swizzle (reader-matched).
// [589824,851968): out = bias (float4 groups).
__global__ __launch_bounds__(256) void prep_kernel(
    const float* __restrict__ x, const float* __restrict__ W,
    const float* __restrict__ bias, char* __restrict__ WT,
    _Float16* __restrict__ Xf, float* __restrict__ out)
{
  int i = blockIdx.x * 256 + threadIdx.x;
  if (i < 524288) {
    int o = i >> 11, k8 = i & 2047;        // k8: 8-elem k-granule within row o
    const float* s = W + ((size_t)o << 14) + ((size_t)k8 << 3);
    f16x8 h;
#pragma unroll
    for (int e = 0; e < 8; ++e) h[e] = (_Float16)s[e];
    int sg  = k8 >> 3;                     // global k-step 0..255
    int seg = k8 & 7;
    char* dst = WT + ((size_t)(sg * 16 + (o >> 4))) * 2048 + seg * 256 + (o & 15) * 16;
    *(f16x8*)dst = h;
  } else if (i < 589824) {
    int j = i - 524288;
    int r = j >> 4, seg = j & 15;
    const float* s = x + r * 128 + seg * 8;
    f16x8 h;
#pragma unroll
    for (int e = 0; e < 8; ++e) h[e] = (_Float16)s[e];
    int segp = seg ^ (r & 7);
    *(f16x8*)(Xf + r * 128 + segp * 8) = h;
  } else {
    int j = i - 589824;                    // float4 idx into out[4096][256]
    int c = (j * 4) & 255;
    ((float4*)out)[j] = *(const float4*)(bias + c);
  }
}

// ------------------------------ GEMM kernel --------------------------------
__global__ __launch_bounds__(256, 2) void gemm_kernel(
    const char* __restrict__ WT, const _Float16* __restrict__ Xf,
    const float* __restrict__ x0, float* __restrict__ out)
{
  __shared__ __align__(16) char x_s[32768];   // x tile [128 r][128 p] f16 swz
  __shared__ float x0t[2048];                 // x0^T [16 f][128 r] f32

  const int bid = blockIdx.x;
  const int mb  = bid >> 4;          // 0..31 : 128-row block
  const int nb  = (bid >> 3) & 1;    // 0..1  : 128-o half
  const int sk  = bid & 7;           // 0..7  : split-K chunk -> XCD-resident

  const int t   = threadIdx.x;
  const int l   = t & 63;
  const int wv  = t >> 6;
  const int wm  = wv >> 1;           // 0..1 : 64-row half
  const int wn  = wv & 1;            // 0..1 : 64-o half
  const int lr  = l & 15;
  const int lg  = l >> 4;
  const int swz = lr & 7;

  // ---- prologue: stage x tile; x0 slice -> regs ----
  const char* XfB = (const char*)Xf + (size_t)mb * 32768;
#pragma unroll
  for (int i = 0; i < 8; ++i)
    gl_lds16(XfB + i * 4096 + t * 16, x_s + i * 4096 + t * 16);

  const int r0 = t >> 1, hf = t & 1;
  const float* x0s = x0 + (size_t)(mb * 128 + r0) * 128 + sk * 16 + hf * 8;
  const float4 xa = *(const float4*)(x0s);
  const float4 xb = *(const float4*)(x0s + 4);
  __syncthreads();                            // x_s ready

  x0t[(hf * 8 + 0) * 128 + r0] = xa.x;
  x0t[(hf * 8 + 1) * 128 + r0] = xa.y;
  x0t[(hf * 8 + 2) * 128 + r0] = xa.z;
  x0t[(hf * 8 + 3) * 128 + r0] = xa.w;
  x0t[(hf * 8 + 4) * 128 + r0] = xb.x;
  x0t[(hf * 8 + 5) * 128 + r0] = xb.y;
  x0t[(hf * 8 + 6) * 128 + r0] = xb.z;
  x0t[(hf * 8 + 7) * 128 + r0] = xb.w;

  // x slice -> registers ONCE, then pin (asm-defined values cannot be
  // rematerialized from LDS -> allocator must keep them resident).
  f16x8 xr[4][2][2];
  const int xrb = (wm * 64 + lr) * 256;
#pragma unroll
  for (int m = 0; m < 4; ++m)
#pragma unroll
    for (int h = 0; h < 2; ++h)
#pragma unroll
      for (int tt = 0; tt < 2; ++tt)
        xr[m][h][tt] = *(const f16x8*)(x_s + xrb + m * 4096 +
                                       (((h * 8 + tt * 4 + lg) ^ swz) << 4));
#pragma unroll
  for (int m = 0; m < 4; ++m)
#pragma unroll
    for (int h = 0; h < 2; ++h)
#pragma unroll
      for (int tt = 0; tt < 2; ++tt)
        asm volatile("" : "+v"(xr[m][h][tt]));

  __syncthreads();                            // x0t visible to all waves
  // (no barriers from here on)

  // per-lane W stream pointer: kstep base sk*32, o-group nb*8 + wn*4
  const char* wt = WT + ((size_t)(sk * 32) * 16 + nb * 8 + wn * 4) * 2048 + l * 16;
  const int x0i = wm * 64 + lr;

  f32x4 acc[4][4] = {};
  f16x8 bwA[4][2], bwB[4][2];
  _Float16 sh[4];

  // prime: step 0 -> bwA
#pragma unroll
  for (int nI = 0; nI < 4; ++nI)
#pragma unroll
    for (int tt = 0; tt < 2; ++tt)
      bwA[nI][tt] = *(const f16x8*)(wt + nI * 2048 + tt * 1024);

#define MFMA_STEP(BW, PH) \
  _Pragma("unroll") \
  for (int m = 0; m < 4; ++m) { \
    _Pragma("unroll") \
    for (int tt = 0; tt < 2; ++tt) { \
      f16x8 av = xr[m][PH][tt] * sh[m]; \
      _Pragma("unroll") \
      for (int nI = 0; nI < 4; ++nI) \
        acc[m][nI] = __builtin_amdgcn_mfma_f32_16x16x32_f16( \
            av, BW[nI][tt], acc[m][nI], 0, 0, 0); \
    } \
  }

  for (int s = 0; s < 32; s += 2) {
    // prefetch step s+1 (same f, ph=1) into bwB
    const char* wt1 = wt + 32768;
#pragma unroll
    for (int nI = 0; nI < 4; ++nI)
#pragma unroll
      for (int tt = 0; tt < 2; ++tt)
        bwB[nI][tt] = *(const f16x8*)(wt1 + nI * 2048 + tt * 1024);

#pragma unroll
    for (int m = 0; m < 4; ++m)
      sh[m] = (_Float16)x0t[(s >> 1) * 128 + x0i + m * 16];

    MFMA_STEP(bwA, 0)

    // prefetch step s+2 into bwA (final iter overshoots into Xf region of
    // ws — valid memory, values never consumed)
    const char* wt2 = wt + 65536;
#pragma unroll
    for (int nI = 0; nI < 4; ++nI)
#pragma unroll
      for (int tt = 0; tt < 2; ++tt)
        bwA[nI][tt] = *(const f16x8*)(wt2 + nI * 2048 + tt * 1024);

    MFMA_STEP(bwB, 1)

    wt += 65536;
  }
#undef MFMA_STEP

  // ---- epilogue: split-K accumulate (out pre-initialized to bias) ----
  // C/D layout: col = lane&15, row = (lane>>4)*4 + reg
  float* op = out + (size_t)(mb * 128 + wm * 64 + lg * 4) * 256 +
              nb * 128 + wn * 64 + lr;
#pragma unroll
  for (int m = 0; m < 4; ++m)
#pragma unroll
    for (int nI = 0; nI < 4; ++nI)
#pragma unroll
      for (int r = 0; r < 4; ++r)
        unsafeAtomicAdd(op + (size_t)(m * 16 + r) * 256 + nI * 16,
                        acc[m][nI][r]);
}

// --------------------------- fallback (no ws) ------------------------------
__global__ __launch_bounds__(256) void naive_kernel(
    const float* __restrict__ x0, const float* __restrict__ x,
    const float* __restrict__ W, const float* __restrict__ bias,
    float* __restrict__ out)
{
  __shared__ float x0_s[16][128];
  __shared__ float x_s[16][128];
  const int tid = threadIdx.x;
  const int b0  = blockIdx.x * 16;
  for (int i = tid; i < 16 * 128; i += 256) {
    int bb = i >> 7, c = i & 127;
    x0_s[bb][c] = x0[(size_t)(b0 + bb) * 128 + c];
    x_s[bb][c]  = x[(size_t)(b0 + bb) * 128 + c];
  }
  __syncthreads();
  const int lane = tid & 63, wv = tid >> 6;
  for (int o = wv; o < 256; o += 4) {
    float acc[16];
#pragma unroll
    for (int bb = 0; bb < 16; ++bb) acc[bb] = 0.f;
    for (int it = 0; it < 256; ++it) {
      int k = it * 64 + lane;
      float wval = W[(size_t)o * 16384 + k];
      int f = k >> 7, p = k & 127;
#pragma unroll
      for (int bb = 0; bb < 16; ++bb)
        acc[bb] += wval * (x0_s[bb][f] * x_s[bb][p]);
    }
#pragma unroll
    for (int bb = 0; bb < 16; ++bb) {
      float v = acc[bb];
      for (int off = 32; off; off >>= 1) v += __shfl_down(v, off);
      if (lane == 0) out[(size_t)(b0 + bb) * 256 + o] = v + bias[o];
    }
  }
}

// ------------------------------- launcher ----------------------------------
extern "C" void kernel_launch(void* const* d_in, const int* in_sizes, int n_in,
                              void* d_out, int out_size, void* d_ws,
                              size_t ws_size, hipStream_t stream)
{
  const float* x0   = (const float*)d_in[0];
  const float* x    = (const float*)d_in[1];
  const float* W    = (const float*)d_in[2];
  const float* bias = (const float*)d_in[3];
  float* out = (float*)d_out;

  if (ws_size >= (size_t)WS_NEEDED) {
    char*     WT = (char*)d_ws + WS_WT_OFF;
    _Float16* Xf = (_Float16*)((char*)d_ws + WS_XF_OFF);
    prep_kernel<<<3328, 256, 0, stream>>>(x, W, bias, WT, Xf, out);
    gemm_kernel<<<512, 256, 0, stream>>>(WT, Xf, x0, out);
  } else {
    naive_kernel<<<256, 256, 0, stream>>>(x0, x, W, bias, out);
  }
}

// Round 10
// 52.976 us; speedup vs baseline: 1.1369x; 1.1341x over previous
//
#include <hip/hip_runtime.h>

// ---------------------------------------------------------------------------
// out[b,o] = sum_{f,p} x0[b,f]*x[b,p]*W[o,f,p] + bias[o]
//   == GEMM C[4096,256] = A[4096,16384] * W^T,  A[b,f*128+p] = x0[b,f]*x[b,p]
// R10: in-block split-K, wave-private pipelines. 512 thr / 8 waves; wave w
// owns k in [w*2048,(w+1)*2048) of ONE 64x64 output tile. W streamed through
// a per-wave 3-slot x 4KB LDS ring via global_load_lds with counted vmcnt(8)
// (never 0) -- slots are wave-private so the K-loop has ZERO barriers (kills
// the R1/R3/R6/R7 lockstep stall). No atomics: 8 partial tiles reduced in
// LDS, plain coalesced f32 stores (WRITE 32MB -> 4MB; R1..R9 plateaued at
// the ~160 G-atomic/s ceiling). W prep-laid granule-major: staging = linear
// 1KB chunks, B ds_read_b128 naturally 2-way (free). A = R7-proven swizzled
// x_s. x0 = f16 [f][row] LDS table (broadcast reads). Grid 256 (64mb x 4ob),
// ob=bid&3 -> per-XCD 2MB W slice L2-resident. 1 blk/CU, 2 waves/SIMD.
// ---------------------------------------------------------------------------

typedef _Float16 f16x8 __attribute__((ext_vector_type(8)));
typedef float    f32x4 __attribute__((ext_vector_type(4)));

#define WS_WT_OFF  0            // WT2: 8 MB, granule-major fragment order
#define WS_XF_OFF  8388608      // Xf : 1 MB, x f16 seg-XOR (R7 layout)
#define WS_X0_OFF  9437184      // X0T: 1 MB, x0 f16 [mb][f][row]
#define WS_NEEDED  10485760

__device__ __forceinline__ void gl_lds16(const void* g, void* l) {
  __builtin_amdgcn_global_load_lds(
      (const __attribute__((address_space(1))) void*)g,
      (__attribute__((address_space(3))) void*)l, 16, 0, 0);
}

#define VMW(N) asm volatile("s_waitcnt vmcnt(" #N ")" ::: "memory")

// ------------------------------ prep kernel --------------------------------
// [0,524288): W f32->f16, granule-major: k8=k/8, ks=k8>>2, g=k8&3, ob=o>>6,
//   o6=o&63 -> WT2 f16 idx = ((ob*512+ks)*4+g)*512 + o6*8. One staging instr
//   covers one (window,granule) = 1KB contiguous; B-read lanes hit 2-way max.
// [524288,589824): x f32->f16 + 16B-seg XOR keyed row&7 (R7-proven).
// [589824,655360): x0 f32->f16 transposed per 64-row block: [mb][f][row].
__global__ __launch_bounds__(256) void prep_kernel(
    const float* __restrict__ x0, const float* __restrict__ x,
    const float* __restrict__ W, _Float16* __restrict__ WT2,
    _Float16* __restrict__ Xf, _Float16* __restrict__ X0T)
{
  int i = blockIdx.x * 256 + threadIdx.x;
  if (i < 524288) {
    int o = i >> 11, k8 = i & 2047;
    const float* s = W + ((size_t)o << 14) + ((size_t)k8 << 3);
    f16x8 h;
#pragma unroll
    for (int e = 0; e < 8; ++e) h[e] = (_Float16)s[e];
    int ks = k8 >> 2, g = k8 & 3, ob = o >> 6, o6 = o & 63;
    *(f16x8*)(WT2 + ((size_t)((ob * 512 + ks) * 4 + g)) * 512 + o6 * 8) = h;
  } else if (i < 589824) {
    int j = i - 524288;
    int r = j >> 4, seg = j & 15;
    const float* s = x + r * 128 + seg * 8;
    f16x8 h;
#pragma unroll
    for (int e = 0; e < 8; ++e) h[e] = (_Float16)s[e];
    int segp = seg ^ (r & 7);
    *(f16x8*)(Xf + r * 128 + segp * 8) = h;
  } else {
    int j = i - 589824;                 // 8 consecutive rows of one (mb,f)
    int mb = j >> 10, rem = j & 1023;
    int f = rem >> 3, r8 = rem & 7;
    f16x8 h;
#pragma unroll
    for (int e = 0; e < 8; ++e)
      h[e] = (_Float16)x0[(size_t)(mb * 64 + r8 * 8 + e) * 128 + f];
    *(f16x8*)(X0T + (size_t)mb * 8192 + f * 64 + r8 * 8) = h;
  }
}

// ------------------------------ GEMM kernel --------------------------------
// smem map: [0,98304) 8 x (3 x 4KB) wave-private W rings;
//           [98304,114688) x_s [64 r][128 p] f16 swz; [114688,131072) x0T
//           [128 f][64 r] f16. Epilogue reuses all of it: 8 regions of
//           64 col x 272B (17408 B each) = 139264 B total.
__global__ __launch_bounds__(512, 2) void gemm_kernel(
    const _Float16* __restrict__ WT2, const _Float16* __restrict__ Xf,
    const _Float16* __restrict__ X0T, const float* __restrict__ bias,
    float* __restrict__ out)
{
  __shared__ __align__(16) char smem[139264];

  const int bid = blockIdx.x;
  const int mb  = bid >> 2;          // 0..63 : 64-row block
  const int ob  = bid & 3;           // 0..3  : 64-o block (XCD-resident W)

  const int t  = threadIdx.x;
  const int l  = t & 63;
  const int wv = t >> 6;             // wave = k-chunk owner
  const int lr = l & 15;
  const int lg = l >> 4;
  const int l16 = l * 16;
  const int slotbase = wv * 12288;

  // wave's W stream base: k-window = wv*64 + ksl, each window 4096 B
  const char* wsrc = (const char*)WT2 +
      ((size_t)(ob * 512 + wv * 64)) * 4096;

  // ---- prologue: x_s + x0T (block-cooperative) , W slots 0,1 (per-wave) ---
  const char* xsb = (const char*)Xf + (size_t)mb * 16384;
  gl_lds16(xsb + 0 * 8192 + t * 16, smem + 98304 + 0 * 8192 + t * 16);
  gl_lds16(xsb + 1 * 8192 + t * 16, smem + 98304 + 1 * 8192 + t * 16);
  const char* x0b = (const char*)X0T + (size_t)mb * 16384;
  gl_lds16(x0b + 0 * 8192 + t * 16, smem + 114688 + 0 * 8192 + t * 16);
  gl_lds16(x0b + 1 * 8192 + t * 16, smem + 114688 + 1 * 8192 + t * 16);
#pragma unroll
  for (int i = 0; i < 4; ++i)
    gl_lds16(wsrc + 0 * 4096 + i * 1024 + l16,
             smem + slotbase + 0 * 4096 + i * 1024 + l16);
#pragma unroll
  for (int i = 0; i < 4; ++i)
    gl_lds16(wsrc + 1 * 4096 + i * 1024 + l16,
             smem + slotbase + 1 * 4096 + i * 1024 + l16);
  VMW(8);                              // own x/x0 rounds retired
  __builtin_amdgcn_s_barrier();        // all waves' x/x0 parts in LDS

  f32x4 acc[4][4] = {};
  _Float16 sh[4];

  // STEP(P,RD,ST,STG,VMC): ks = kk+P. Stage window ks+2 into literal slot ST,
  // counted wait (slot RD ready), 4 A-reads + 4 B-reads + 16 MFMA. No barrier.
#define STEP(P, RD, ST, STG, VMC) { \
    if (STG) { \
      _Pragma("unroll") \
      for (int i = 0; i < 4; ++i) \
        gl_lds16(wsrc + (size_t)(kk + (P) + 2) * 4096 + i * 1024 + l16, \
                 smem + slotbase + (ST) * 4096 + i * 1024 + l16); \
    } \
    VMW(VMC); \
    if (((P) & 3) == 0) { \
      const int fb = 114688 + (wv * 16 + kk4 + ((P) >> 2)) * 128; \
      _Pragma("unroll") \
      for (int m = 0; m < 4; ++m) \
        sh[m] = *(const _Float16*)(smem + fb + (m * 16 + lr) * 2); \
    } \
    f16x8 bw[4]; \
    _Pragma("unroll") \
    for (int n = 0; n < 4; ++n) \
      bw[n] = *(const f16x8*)(smem + slotbase + (RD) * 4096 + lg * 1024 + \
                              (n * 16 + lr) * 16); \
    _Pragma("unroll") \
    for (int m = 0; m < 4; ++m) { \
      f16x8 xa = *(const f16x8*)(smem + 98304 + (m * 16 + lr) * 256 + \
                  (((((P) & 3) * 4 + lg) ^ (lr & 7)) << 4)); \
      f16x8 av = xa * sh[m]; \
      _Pragma("unroll") \
      for (int n = 0; n < 4; ++n) \
        acc[m][n] = __builtin_amdgcn_mfma_f32_16x16x32_f16( \
            av, bw[n], acc[m][n], 0, 0, 0); \
    } \
  }

  for (int kk = 0; kk < 60; kk += 12) {
    const int kk4 = kk >> 2;
    STEP(0, 0, 2, 1, 8)  STEP(1, 1, 0, 1, 8)  STEP(2, 2, 1, 1, 8)
    STEP(3, 0, 2, 1, 8)  STEP(4, 1, 0, 1, 8)  STEP(5, 2, 1, 1, 8)
    STEP(6, 0, 2, 1, 8)  STEP(7, 1, 0, 1, 8)  STEP(8, 2, 1, 1, 8)
    STEP(9, 0, 2, 1, 8)  STEP(10, 1, 0, 1, 8) STEP(11, 2, 1, 1, 8)
  }
  {
    const int kk = 60, kk4 = 15;
    STEP(0, 0, 2, 1, 8)   // ks 60, stages 62
    STEP(1, 1, 0, 1, 8)   // ks 61, stages 63
    STEP(2, 2, 0, 0, 4)   // ks 62
    STEP(3, 0, 0, 0, 0)   // ks 63
  }
#undef STEP

  // ---- epilogue: LDS reduce of 8 partials, plain f32 store (no atomics) ---
  asm volatile("s_waitcnt vmcnt(0) lgkmcnt(0)" ::: "memory");
  __builtin_amdgcn_s_barrier();        // everyone done reading x_s/slots

  // region wv: [col(64) x 272B][row(64) f32]; acc frag rows rr contiguous
#pragma unroll
  for (int m = 0; m < 4; ++m)
#pragma unroll
    for (int n = 0; n < 4; ++n)
      *(f32x4*)(smem + wv * 17408 + (n * 16 + lr) * 272 +
                (m * 16 + lg * 4) * 4) = acc[m][n];

  asm volatile("s_waitcnt lgkmcnt(0)" ::: "memory");
  __builtin_amdgcn_s_barrier();

  {
    const int row = t >> 3, c8 = (t & 7) * 8;
    float v[8];
#pragma unroll
    for (int c = 0; c < 8; ++c) {
      float s = 0.f;
#pragma unroll
      for (int w = 0; w < 8; ++w)
        s += *(const float*)(smem + w * 17408 + (c8 + c) * 272 + row * 4);
      v[c] = s;
    }
    const float4 b0 = *(const float4*)(bias + ob * 64 + c8);
    const float4 b1 = *(const float4*)(bias + ob * 64 + c8 + 4);
    float* op = out + (size_t)(mb * 64 + row) * 256 + ob * 64 + c8;
    float4 o0 = {v[0] + b0.x, v[1] + b0.y, v[2] + b0.z, v[3] + b0.w};
    float4 o1 = {v[4] + b1.x, v[5] + b1.y, v[6] + b1.z, v[7] + b1.w};
    *(float4*)(op)     = o0;
    *(float4*)(op + 4) = o1;
  }
}

// --------------------------- fallback (no ws) ------------------------------
__global__ __launch_bounds__(256) void naive_kernel(
    const float* __restrict__ x0, const float* __restrict__ x,
    const float* __restrict__ W, const float* __restrict__ bias,
    float* __restrict__ out)
{
  __shared__ float x0_s[16][128];
  __shared__ float x_s[16][128];
  const int tid = threadIdx.x;
  const int b0  = blockIdx.x * 16;
  for (int i = tid; i < 16 * 128; i += 256) {
    int bb = i >> 7, c = i & 127;
    x0_s[bb][c] = x0[(size_t)(b0 + bb) * 128 + c];
    x_s[bb][c]  = x[(size_t)(b0 + bb) * 128 + c];
  }
  __syncthreads();
  const int lane = tid & 63, wv = tid >> 6;
  for (int o = wv; o < 256; o += 4) {
    float acc[16];
#pragma unroll
    for (int bb = 0; bb < 16; ++bb) acc[bb] = 0.f;
    for (int it = 0; it < 256; ++it) {
      int k = it * 64 + lane;
      float wval = W[(size_t)o * 16384 + k];
      int f = k >> 7, p = k & 127;
#pragma unroll
      for (int bb = 0; bb < 16; ++bb)
        acc[bb] += wval * (x0_s[bb][f] * x_s[bb][p]);
    }
#pragma unroll
    for (int bb = 0; bb < 16; ++bb) {
      float v = acc[bb];
      for (int off = 32; off; off >>= 1) v += __shfl_down(v, off);
      if (lane == 0) out[(size_t)(b0 + bb) * 256 + o] = v + bias[o];
    }
  }
}

// ------------------------------- launcher ----------------------------------
extern "C" void kernel_launch(void* const* d_in, const int* in_sizes, int n_in,
                              void* d_out, int out_size, void* d_ws,
                              size_t ws_size, hipStream_t stream)
{
  const float* x0   = (const float*)d_in[0];
  const float* x    = (const float*)d_in[1];
  const float* W    = (const float*)d_in[2];
  const float* bias = (const float*)d_in[3];
  float* out = (float*)d_out;

  if (ws_size >= (size_t)WS_NEEDED) {
    _Float16* WT2 = (_Float16*)((char*)d_ws + WS_WT_OFF);
    _Float16* Xf  = (_Float16*)((char*)d_ws + WS_XF_OFF);
    _Float16* X0T = (_Float16*)((char*)d_ws + WS_X0_OFF);
    prep_kernel<<<2560, 256, 0, stream>>>(x0, x, W, WT2, Xf, X0T);
    gemm_kernel<<<256, 512, 0, stream>>>(WT2, Xf, X0T, bias, out);
  } else {
    naive_kernel<<<256, 256, 0, stream>>>(x0, x, W, bias, out);
  }
}

// Round 11
// 49.412 us; speedup vs baseline: 1.2189x; 1.0721x over previous
//
#include <hip/hip_runtime.h>

// ---------------------------------------------------------------------------
// out[b,o] = sum_{f,p} x0[b,f]*x[b,p]*W[o,f,p] + bias[o]
//   == GEMM C[4096,256] = A[4096,16384] * W^T,  A[b,f*128+p] = x0[b,f]*x[b,p]
// R11 = R10 (wave-private ring, no barriers/atomics in K-loop) + LDS-traffic
// surgery. R10 audit: per-CU LDS content = B 24.6K + A 12.3K + sh-scalar
// 11.9K + staging ~16K cyc = ~27us floor (observed 44 = 1.6x slop).
//   (a) q-major window order (prep reindex): all 16 f-windows at fixed q
//       share x-frags -> xa[4] (16 VGPR) loaded 4x/kernel, A-reads /16.
//   (b) x0 row-major swizzled f16 table; x0v[4] f16x8 per half-q + static
//       element extract -> 2048 scalar sh reads -> 32 b128 reads.
//   (c) cross-window B pipeline: at WI, VMW + read WI+1 -> other named buf,
//       then MFMA WI (ds-latency hidden under MFMA). Ring-3, stage-3-ahead,
//       vmcnt(8) never 0 in loop.
// Epilogue: LDS reduce of 8 wave partials + plain f32 store (no atomics).
// ---------------------------------------------------------------------------

typedef _Float16 f16x8 __attribute__((ext_vector_type(8)));
typedef float    f32x4 __attribute__((ext_vector_type(4)));

#define WS_WT_OFF  0            // WT2 : 8 MB, q-major fragment order
#define WS_XF_OFF  8388608      // Xf  : 1 MB, x f16 seg-XOR (R7 layout)
#define WS_X0_OFF  9437184      // X0T2: 1 MB, x0 f16 [mb][row][f] swizzled
#define WS_NEEDED  10485760

__device__ __forceinline__ void gl_lds16(const void* g, void* l) {
  __builtin_amdgcn_global_load_lds(
      (const __attribute__((address_space(1))) void*)g,
      (__attribute__((address_space(3))) void*)l, 16, 0, 0);
}

#define VMW(N) asm volatile("s_waitcnt vmcnt(" #N ")" ::: "memory")

// ------------------------------ prep kernel --------------------------------
// [0,524288): W f32->f16, q-major window order. k8 granule: ks=k8>>2 g=k8&3;
//   wv=ks>>6; r=ks&63; f=r>>2; q=r&3; widx=q*16+f;
//   WT2 f16 idx = ((ob*512 + wv*64 + widx)*4 + g)*512 + (o&63)*8.
// [524288,589824): x f32->f16 + 16B-seg XOR keyed row&7 (unchanged).
// [589824,655360): x0 f16 [mb][row(64)][f(128)], 16B f-blocks XOR'd by row&7.
__global__ __launch_bounds__(256) void prep_kernel(
    const float* __restrict__ x0, const float* __restrict__ x,
    const float* __restrict__ W, _Float16* __restrict__ WT2,
    _Float16* __restrict__ Xf, _Float16* __restrict__ X0T2)
{
  int i = blockIdx.x * 256 + threadIdx.x;
  if (i < 524288) {
    int o = i >> 11, k8 = i & 2047;
    const float* s = W + ((size_t)o << 14) + ((size_t)k8 << 3);
    f16x8 h;
#pragma unroll
    for (int e = 0; e < 8; ++e) h[e] = (_Float16)s[e];
    int ks = k8 >> 2, g = k8 & 3, ob = o >> 6, o6 = o & 63;
    int wv = ks >> 6, r = ks & 63, f = r >> 2, q = r & 3;
    int widx = q * 16 + f;
    *(f16x8*)(WT2 + ((size_t)((ob * 512 + wv * 64 + widx) * 4 + g)) * 512 +
              o6 * 8) = h;
  } else if (i < 589824) {
    int j = i - 524288;
    int r = j >> 4, seg = j & 15;
    const float* s = x + r * 128 + seg * 8;
    f16x8 h;
#pragma unroll
    for (int e = 0; e < 8; ++e) h[e] = (_Float16)s[e];
    int segp = seg ^ (r & 7);
    *(f16x8*)(Xf + r * 128 + segp * 8) = h;
  } else {
    int j = i - 589824;                // (mb, row, 8-f block)
    int mb = j >> 10, rem = j & 1023;
    int row = rem >> 4, jb = rem & 15;
    f16x8 h;
#pragma unroll
    for (int e = 0; e < 8; ++e)
      h[e] = (_Float16)x0[(size_t)(mb * 64 + row) * 128 + jb * 8 + e];
    *(f16x8*)(X0T2 + (size_t)mb * 8192 + row * 128 + (jb ^ (row & 7)) * 8) = h;
  }
}

// ------------------------------ GEMM kernel --------------------------------
// smem: [0,98304) 8 x (3 x 4KB) wave-private W rings; [98304,114688) x_s
// [64r][128p] swz; [114688,131072) x0 [64r][128f] swz. Epilogue reuses all:
// 8 regions x 17408 B.
__global__ __launch_bounds__(512, 2) void gemm_kernel(
    const _Float16* __restrict__ WT2, const _Float16* __restrict__ Xf,
    const _Float16* __restrict__ X0T2, const float* __restrict__ bias,
    float* __restrict__ out)
{
  __shared__ __align__(16) char smem[139264];

  const int bid = blockIdx.x;
  const int mb  = bid >> 2;          // 0..63 : 64-row block
  const int ob  = bid & 3;           // 0..3  : 64-o block (XCD-resident W)

  const int t  = threadIdx.x;
  const int l  = t & 63;
  const int wv = t >> 6;             // wave = k-chunk owner (f wv*16..+15)
  const int lr = l & 15;
  const int lg = l >> 4;
  const int l16 = l * 16;
  const int swz = lr & 7;
  const int slotbase = wv * 12288;

  const char* wsrc = (const char*)WT2 + ((size_t)(ob * 512 + wv * 64)) * 4096;

  // ---- prologue: x_s, x0 (block-coop), W windows 0..2 (per-wave) ----
  const char* xsb = (const char*)Xf + (size_t)mb * 16384;
  gl_lds16(xsb + 0 * 8192 + t * 16, smem + 98304 + 0 * 8192 + t * 16);
  gl_lds16(xsb + 1 * 8192 + t * 16, smem + 98304 + 1 * 8192 + t * 16);
  const char* x0b = (const char*)X0T2 + (size_t)mb * 16384;
  gl_lds16(x0b + 0 * 8192 + t * 16, smem + 114688 + 0 * 8192 + t * 16);
  gl_lds16(x0b + 1 * 8192 + t * 16, smem + 114688 + 1 * 8192 + t * 16);
#pragma unroll
  for (int w = 0; w < 3; ++w)
#pragma unroll
    for (int i = 0; i < 4; ++i)
      gl_lds16(wsrc + w * 4096 + i * 1024 + l16,
               smem + slotbase + w * 4096 + i * 1024 + l16);
  VMW(8);                              // own x/x0 + window0 retired
  __builtin_amdgcn_s_barrier();        // all waves' x/x0 in LDS

  f32x4 acc[4][4] = {};
  f16x8 xa[4], x0v[4], bwA[4], bwB[4];

  // xa: Q=0 fragments; x0v: half 0 (f 0..7); bwA: window 0
#pragma unroll
  for (int m = 0; m < 4; ++m)
    xa[m] = *(const f16x8*)(smem + 98304 + (m * 16 + lr) * 256 +
                            (((0 * 4 + lg) ^ swz) << 4));
#pragma unroll
  for (int m = 0; m < 4; ++m)
    x0v[m] = *(const f16x8*)(smem + 114688 + (m * 16 + lr) * 256 +
                             (((wv * 2 + 0) ^ swz) << 4));
#pragma unroll
  for (int n = 0; n < 4; ++n)
    bwA[n] = *(const f16x8*)(smem + slotbase + 0 * 4096 + lg * 1024 +
                             (n * 16 + lr) * 16);

  // STEP(WI, BUFRD, BUFWR, STG, VMC):
  //   stage window WI+3 -> slot WI%3 (just freed: its data is in BUFRD);
  //   VMW -> window WI+1 data in LDS; read WI+1 -> BUFWR;
  //   av from xa/x0v; boundary reloads; 16 MFMA from BUFRD.
#define STEP(WI, BUFRD, BUFWR, STG, VMC) { \
    if (STG) { \
      _Pragma("unroll") \
      for (int i = 0; i < 4; ++i) \
        gl_lds16(wsrc + ((WI) + 3) * 4096 + i * 1024 + l16, \
                 smem + slotbase + ((WI) % 3) * 4096 + i * 1024 + l16); \
    } \
    VMW(VMC); \
    if ((WI) < 63) { \
      _Pragma("unroll") \
      for (int n = 0; n < 4; ++n) \
        BUFWR[n] = *(const f16x8*)(smem + slotbase + (((WI) + 1) % 3) * 4096 + \
                                   lg * 1024 + (n * 16 + lr) * 16); \
    } \
    f16x8 av[4]; \
    _Pragma("unroll") \
    for (int m = 0; m < 4; ++m) { \
      _Float16 sh = x0v[m][(WI) & 7]; \
      av[m] = xa[m] * sh; \
    } \
    if ((((WI) + 1) & 15) == 0 && (WI) < 63) { \
      _Pragma("unroll") \
      for (int m = 0; m < 4; ++m) \
        xa[m] = *(const f16x8*)(smem + 98304 + (m * 16 + lr) * 256 + \
                 ((((((WI) + 1) >> 4) * 4 + lg) ^ swz) << 4)); \
    } \
    if ((((WI) + 1) & 7) == 0 && (WI) < 63) { \
      _Pragma("unroll") \
      for (int m = 0; m < 4; ++m) \
        x0v[m] = *(const f16x8*)(smem + 114688 + (m * 16 + lr) * 256 + \
                  (((wv * 2 + ((((WI) + 1) >> 3) & 1)) ^ swz) << 4)); \
    } \
    _Pragma("unroll") \
    for (int m = 0; m < 4; ++m) { \
      _Pragma("unroll") \
      for (int n = 0; n < 4; ++n) \
        acc[m][n] = __builtin_amdgcn_mfma_f32_16x16x32_f16( \
            av[m], BUFRD[n], acc[m][n], 0, 0, 0); \
    } \
  }

#define SE(WI, STG, VMC) STEP(WI, bwA, bwB, STG, VMC)
#define SO(WI, STG, VMC) STEP(WI, bwB, bwA, STG, VMC)

  SE(0,1,8)  SO(1,1,8)  SE(2,1,8)  SO(3,1,8)  SE(4,1,8)  SO(5,1,8)
  SE(6,1,8)  SO(7,1,8)  SE(8,1,8)  SO(9,1,8)  SE(10,1,8) SO(11,1,8)
  SE(12,1,8) SO(13,1,8) SE(14,1,8) SO(15,1,8) SE(16,1,8) SO(17,1,8)
  SE(18,1,8) SO(19,1,8) SE(20,1,8) SO(21,1,8) SE(22,1,8) SO(23,1,8)
  SE(24,1,8) SO(25,1,8) SE(26,1,8) SO(27,1,8) SE(28,1,8) SO(29,1,8)
  SE(30,1,8) SO(31,1,8) SE(32,1,8) SO(33,1,8) SE(34,1,8) SO(35,1,8)
  SE(36,1,8) SO(37,1,8) SE(38,1,8) SO(39,1,8) SE(40,1,8) SO(41,1,8)
  SE(42,1,8) SO(43,1,8) SE(44,1,8) SO(45,1,8) SE(46,1,8) SO(47,1,8)
  SE(48,1,8) SO(49,1,8) SE(50,1,8) SO(51,1,8) SE(52,1,8) SO(53,1,8)
  SE(54,1,8) SO(55,1,8) SE(56,1,8) SO(57,1,8) SE(58,1,8) SO(59,1,8)
  SE(60,1,8) SO(61,0,4) SE(62,0,0) SO(63,0,0)

#undef SE
#undef SO
#undef STEP

  // ---- epilogue: LDS reduce of 8 partials, plain f32 store (no atomics) ---
  asm volatile("s_waitcnt vmcnt(0) lgkmcnt(0)" ::: "memory");
  __builtin_amdgcn_s_barrier();        // all waves done with rings/x_s/x0

  // region wv: [col(64) x 272B][row(64) f32]
#pragma unroll
  for (int m = 0; m < 4; ++m)
#pragma unroll
    for (int n = 0; n < 4; ++n)
      *(f32x4*)(smem + wv * 17408 + (n * 16 + lr) * 272 +
                (m * 16 + lg * 4) * 4) = acc[m][n];

  asm volatile("s_waitcnt lgkmcnt(0)" ::: "memory");
  __builtin_amdgcn_s_barrier();

  {
    const int row = t >> 3, c8 = (t & 7) * 8;
    float v[8];
#pragma unroll
    for (int c = 0; c < 8; ++c) {
      float s = 0.f;
#pragma unroll
      for (int w = 0; w < 8; ++w)
        s += *(const float*)(smem + w * 17408 + (c8 + c) * 272 + row * 4);
      v[c] = s;
    }
    const float4 b0 = *(const float4*)(bias + ob * 64 + c8);
    const float4 b1 = *(const float4*)(bias + ob * 64 + c8 + 4);
    float* op = out + (size_t)(mb * 64 + row) * 256 + ob * 64 + c8;
    float4 o0 = {v[0] + b0.x, v[1] + b0.y, v[2] + b0.z, v[3] + b0.w};
    float4 o1 = {v[4] + b1.x, v[5] + b1.y, v[6] + b1.z, v[7] + b1.w};
    *(float4*)(op)     = o0;
    *(float4*)(op + 4) = o1;
  }
}

// --------------------------- fallback (no ws) ------------------------------
__global__ __launch_bounds__(256) void naive_kernel(
    const float* __restrict__ x0, const float* __restrict__ x,
    const float* __restrict__ W, const float* __restrict__ bias,
    float* __restrict__ out)
{
  __shared__ float x0_s[16][128];
  __shared__ float x_s[16][128];
  const int tid = threadIdx.x;
  const int b0  = blockIdx.x * 16;
  for (int i = tid; i < 16 * 128; i += 256) {
    int bb = i >> 7, c = i & 127;
    x0_s[bb][c] = x0[(size_t)(b0 + bb) * 128 + c];
    x_s[bb][c]  = x[(size_t)(b0 + bb) * 128 + c];
  }
  __syncthreads();
  const int lane = tid & 63, wv = tid >> 6;
  for (int o = wv; o < 256; o += 4) {
    float acc[16];
#pragma unroll
    for (int bb = 0; bb < 16; ++bb) acc[bb] = 0.f;
    for (int it = 0; it < 256; ++it) {
      int k = it * 64 + lane;
      float wval = W[(size_t)o * 16384 + k];
      int f = k >> 7, p = k & 127;
#pragma unroll
      for (int bb = 0; bb < 16; ++bb)
        acc[bb] += wval * (x0_s[bb][f] * x_s[bb][p]);
    }
#pragma unroll
    for (int bb = 0; bb < 16; ++bb) {
      float v = acc[bb];
      for (int off = 32; off; off >>= 1) v += __shfl_down(v, off);
      if (lane == 0) out[(size_t)(b0 + bb) * 256 + o] = v + bias[o];
    }
  }
}

// ------------------------------- launcher ----------------------------------
extern "C" void kernel_launch(void* const* d_in, const int* in_sizes, int n_in,
                              void* d_out, int out_size, void* d_ws,
                              size_t ws_size, hipStream_t stream)
{
  const float* x0   = (const float*)d_in[0];
  const float* x    = (const float*)d_in[1];
  const float* W    = (const float*)d_in[2];
  const float* bias = (const float*)d_in[3];
  float* out = (float*)d_out;

  if (ws_size >= (size_t)WS_NEEDED) {
    _Float16* WT2  = (_Float16*)((char*)d_ws + WS_WT_OFF);
    _Float16* Xf   = (_Float16*)((char*)d_ws + WS_XF_OFF);
    _Float16* X0T2 = (_Float16*)((char*)d_ws + WS_X0_OFF);
    prep_kernel<<<2560, 256, 0, stream>>>(x0, x, W, WT2, Xf, X0T2);
    gemm_kernel<<<256, 512, 0, stream>>>(WT2, Xf, X0T2, bias, out);
  } else {
    naive_kernel<<<256, 256, 0, stream>>>(x0, x, W, bias, out);
  }
}

// Round 12
// 49.283 us; speedup vs baseline: 1.2221x; 1.0026x over previous
//
#include <hip/hip_runtime.h>

// ---------------------------------------------------------------------------
// out[b,o] = sum_{f,p} x0[b,f]*x[b,p]*W[o,f,p] + bias[o]
//   == GEMM C[4096,256] = A[4096,16384] * W^T,  A[b,f*128+p] = x0[b,f]*x[b,p]
// R12 = R11 minus the W LDS round-trip. R11 hit ~840 GF (the plain-HIP
// 2-phase-class ceiling) with W staged global->LDS->regs; the LDS pipe
// (B-reads + gl_lds writes ~17us content) is the largest removable term.
// R11's q-major window order cut persistent A-state to 32 VGPR (xa[4] +
// x0v[4]), so B can now stream L2->REGISTERS: per window 4 plain
// global_load_dwordx4 into a named 3-buffer ring (literal rotation), issued
// 2 windows (~600cyc) ahead; compiler inserts counted vmcnt automatically
// (no asm, no barriers, no LDS in the K-loop). LDS 139KB (epilogue) forces
// 1 blk/CU -> allocator targets 2 waves/SIMD -> 256-reg budget; need ~170.
// Grid 256 = 64 mb x 4 ob; ob=bid&3 == bid%8&3 -> each XCD reads ONE 2MB
// W slice (L2-resident). Epilogue: in-block LDS reduce of 8 wave partials +
// plain f32 stores (no atomics).
// ---------------------------------------------------------------------------

typedef _Float16 f16x8 __attribute__((ext_vector_type(8)));
typedef float    f32x4 __attribute__((ext_vector_type(4)));

#define WS_WT_OFF  0            // WT2 : 8 MB, q-major fragment order
#define WS_XF_OFF  8388608      // Xf  : 1 MB, x f16 seg-XOR (R7 layout)
#define WS_X0_OFF  9437184      // X0T2: 1 MB, x0 f16 [mb][row][f] swizzled
#define WS_NEEDED  10485760

__device__ __forceinline__ void gl_lds16(const void* g, void* l) {
  __builtin_amdgcn_global_load_lds(
      (const __attribute__((address_space(1))) void*)g,
      (__attribute__((address_space(3))) void*)l, 16, 0, 0);
}

// ------------------------------ prep kernel --------------------------------
// [0,524288): W f32->f16, q-major window order. k8 granule: ks=k8>>2 g=k8&3;
//   wv=ks>>6; r=ks&63; f=r>>2; q=r&3; widx=q*16+f;
//   WT2 f16 idx = ((ob*512 + wv*64 + widx)*4 + g)*512 + (o&63)*8.
// [524288,589824): x f32->f16 + 16B-seg XOR keyed row&7.
// [589824,655360): x0 f16 [mb][row(64)][f(128)], 16B f-blocks XOR'd by row&7.
__global__ __launch_bounds__(256) void prep_kernel(
    const float* __restrict__ x0, const float* __restrict__ x,
    const float* __restrict__ W, _Float16* __restrict__ WT2,
    _Float16* __restrict__ Xf, _Float16* __restrict__ X0T2)
{
  int i = blockIdx.x * 256 + threadIdx.x;
  if (i < 524288) {
    int o = i >> 11, k8 = i & 2047;
    const float* s = W + ((size_t)o << 14) + ((size_t)k8 << 3);
    f16x8 h;
#pragma unroll
    for (int e = 0; e < 8; ++e) h[e] = (_Float16)s[e];
    int ks = k8 >> 2, g = k8 & 3, ob = o >> 6, o6 = o & 63;
    int wv = ks >> 6, r = ks & 63, f = r >> 2, q = r & 3;
    int widx = q * 16 + f;
    *(f16x8*)(WT2 + ((size_t)((ob * 512 + wv * 64 + widx) * 4 + g)) * 512 +
              o6 * 8) = h;
  } else if (i < 589824) {
    int j = i - 524288;
    int r = j >> 4, seg = j & 15;
    const float* s = x + r * 128 + seg * 8;
    f16x8 h;
#pragma unroll
    for (int e = 0; e < 8; ++e) h[e] = (_Float16)s[e];
    int segp = seg ^ (r & 7);
    *(f16x8*)(Xf + r * 128 + segp * 8) = h;
  } else {
    int j = i - 589824;                // (mb, row, 8-f block)
    int mb = j >> 10, rem = j & 1023;
    int row = rem >> 4, jb = rem & 15;
    f16x8 h;
#pragma unroll
    for (int e = 0; e < 8; ++e)
      h[e] = (_Float16)x0[(size_t)(mb * 64 + row) * 128 + jb * 8 + e];
    *(f16x8*)(X0T2 + (size_t)mb * 8192 + row * 128 + (jb ^ (row & 7)) * 8) = h;
  }
}

// ------------------------------ GEMM kernel --------------------------------
// smem compute: [0,16384) x_s [64r][128p] swz; [16384,32768) x0 [64r][128f]
// swz. Epilogue reuses [0,139264): 8 regions x 17408 B.
__global__ __launch_bounds__(512, 2) void gemm_kernel(
    const _Float16* __restrict__ WT2, const _Float16* __restrict__ Xf,
    const _Float16* __restrict__ X0T2, const float* __restrict__ bias,
    float* __restrict__ out)
{
  __shared__ __align__(16) char smem[139264];

  const int bid = blockIdx.x;
  const int mb  = bid >> 2;          // 0..63 : 64-row block
  const int ob  = bid & 3;           // 0..3  : 64-o block (== bid%8&3 -> XCD)

  const int t  = threadIdx.x;
  const int l  = t & 63;
  const int wv = t >> 6;             // wave = k-chunk owner (f wv*16..+15)
  const int lr = l & 15;
  const int lg = l >> 4;
  const int swz = lr & 7;

  const char* wsrc = (const char*)WT2 + ((size_t)(ob * 512 + wv * 64)) * 4096;
  const int wofs = lg * 1024 + lr * 16;   // lane offset within a window

  // ---- prologue: x_s + x0 tables -> LDS (one-time), A-state -> regs ----
  const char* xsb = (const char*)Xf + (size_t)mb * 16384;
  gl_lds16(xsb + 0 * 8192 + t * 16, smem + 0 * 8192 + t * 16);
  gl_lds16(xsb + 1 * 8192 + t * 16, smem + 1 * 8192 + t * 16);
  const char* x0b = (const char*)X0T2 + (size_t)mb * 16384;
  gl_lds16(x0b + 0 * 8192 + t * 16, smem + 16384 + 0 * 8192 + t * 16);
  gl_lds16(x0b + 1 * 8192 + t * 16, smem + 16384 + 1 * 8192 + t * 16);
  __syncthreads();

  f32x4 acc[4][4] = {};
  f16x8 xa[4], x0v[4], bw0[4], bw1[4], bw2[4];

#pragma unroll
  for (int m = 0; m < 4; ++m)
    xa[m] = *(const f16x8*)(smem + (m * 16 + lr) * 256 + ((lg ^ swz) << 4));
#pragma unroll
  for (int m = 0; m < 4; ++m)
    x0v[m] = *(const f16x8*)(smem + 16384 + (m * 16 + lr) * 256 +
                             (((wv * 2) ^ swz) << 4));
  // prime: windows 0,1 -> bw0,bw1 (plain loads; compiler counts vmcnt)
#pragma unroll
  for (int i = 0; i < 4; ++i)
    bw0[i] = *(const f16x8*)(wsrc + 0 * 4096 + i * 256 + wofs);
#pragma unroll
  for (int i = 0; i < 4; ++i)
    bw1[i] = *(const f16x8*)(wsrc + 1 * 4096 + i * 256 + wofs);

  // STEP(WI, BR, BW_, STG): issue window WI+2 -> BW_ ring buf, boundary
  // xa/x0v reloads (for WI+1), 16 MFMA from BR. No asm, no barriers.
#define STEP(WI, BR, BW_, STG) { \
    if (STG) { \
      _Pragma("unroll") \
      for (int i = 0; i < 4; ++i) \
        BW_[i] = *(const f16x8*)(wsrc + ((WI) + 2) * 4096 + i * 256 + wofs); \
    } \
    f16x8 av[4]; \
    _Pragma("unroll") \
    for (int m = 0; m < 4; ++m) \
      av[m] = xa[m] * x0v[m][(WI) & 7]; \
    if ((((WI) + 1) & 15) == 0 && (WI) < 63) { \
      _Pragma("unroll") \
      for (int m = 0; m < 4; ++m) \
        xa[m] = *(const f16x8*)(smem + (m * 16 + lr) * 256 + \
                 ((((((WI) + 1) >> 4) * 4 + lg) ^ swz) << 4)); \
    } \
    if ((((WI) + 1) & 7) == 0 && (WI) < 63) { \
      _Pragma("unroll") \
      for (int m = 0; m < 4; ++m) \
        x0v[m] = *(const f16x8*)(smem + 16384 + (m * 16 + lr) * 256 + \
                  (((wv * 2 + ((((WI) + 1) >> 3) & 1)) ^ swz) << 4)); \
    } \
    _Pragma("unroll") \
    for (int m = 0; m < 4; ++m) { \
      _Pragma("unroll") \
      for (int n = 0; n < 4; ++n) \
        acc[m][n] = __builtin_amdgcn_mfma_f32_16x16x32_f16( \
            av[m], BR[n], acc[m][n], 0, 0, 0); \
    } \
  }

#define S0(WI, STG) STEP(WI, bw0, bw2, STG)
#define S1(WI, STG) STEP(WI, bw1, bw0, STG)
#define S2(WI, STG) STEP(WI, bw2, bw1, STG)

  S0(0,1)  S1(1,1)  S2(2,1)  S0(3,1)  S1(4,1)  S2(5,1)
  S0(6,1)  S1(7,1)  S2(8,1)  S0(9,1)  S1(10,1) S2(11,1)
  S0(12,1) S1(13,1) S2(14,1) S0(15,1) S1(16,1) S2(17,1)
  S0(18,1) S1(19,1) S2(20,1) S0(21,1) S1(22,1) S2(23,1)
  S0(24,1) S1(25,1) S2(26,1) S0(27,1) S1(28,1) S2(29,1)
  S0(30,1) S1(31,1) S2(32,1) S0(33,1) S1(34,1) S2(35,1)
  S0(36,1) S1(37,1) S2(38,1) S0(39,1) S1(40,1) S2(41,1)
  S0(42,1) S1(43,1) S2(44,1) S0(45,1) S1(46,1) S2(47,1)
  S0(48,1) S1(49,1) S2(50,1) S0(51,1) S1(52,1) S2(53,1)
  S0(54,1) S1(55,1) S2(56,1) S0(57,1) S1(58,1) S2(59,1)
  S0(60,1) S1(61,1) S2(62,0) S0(63,0)

#undef S0
#undef S1
#undef S2
#undef STEP

  // ---- epilogue: LDS reduce of 8 partials, plain f32 store (no atomics) ---
  __syncthreads();                     // all waves done reading x_s/x0 LDS

  // region wv: [col(64) x 272B][row(64) f32]
#pragma unroll
  for (int m = 0; m < 4; ++m)
#pragma unroll
    for (int n = 0; n < 4; ++n)
      *(f32x4*)(smem + wv * 17408 + (n * 16 + lr) * 272 +
                (m * 16 + lg * 4) * 4) = acc[m][n];

  __syncthreads();

  {
    const int row = t >> 3, c8 = (t & 7) * 8;
    float v[8];
#pragma unroll
    for (int c = 0; c < 8; ++c) {
      float s = 0.f;
#pragma unroll
      for (int w = 0; w < 8; ++w)
        s += *(const float*)(smem + w * 17408 + (c8 + c) * 272 + row * 4);
      v[c] = s;
    }
    const float4 b0 = *(const float4*)(bias + ob * 64 + c8);
    const float4 b1 = *(const float4*)(bias + ob * 64 + c8 + 4);
    float* op = out + (size_t)(mb * 64 + row) * 256 + ob * 64 + c8;
    float4 o0 = {v[0] + b0.x, v[1] + b0.y, v[2] + b0.z, v[3] + b0.w};
    float4 o1 = {v[4] + b1.x, v[5] + b1.y, v[6] + b1.z, v[7] + b1.w};
    *(float4*)(op)     = o0;
    *(float4*)(op + 4) = o1;
  }
}

// --------------------------- fallback (no ws) ------------------------------
__global__ __launch_bounds__(256) void naive_kernel(
    const float* __restrict__ x0, const float* __restrict__ x,
    const float* __restrict__ W, const float* __restrict__ bias,
    float* __restrict__ out)
{
  __shared__ float x0_s[16][128];
  __shared__ float x_s[16][128];
  const int tid = threadIdx.x;
  const int b0  = blockIdx.x * 16;
  for (int i = tid; i < 16 * 128; i += 256) {
    int bb = i >> 7, c = i & 127;
    x0_s[bb][c] = x0[(size_t)(b0 + bb) * 128 + c];
    x_s[bb][c]  = x[(size_t)(b0 + bb) * 128 + c];
  }
  __syncthreads();
  const int lane = tid & 63, wv = tid >> 6;
  for (int o = wv; o < 256; o += 4) {
    float acc[16];
#pragma unroll
    for (int bb = 0; bb < 16; ++bb) acc[bb] = 0.f;
    for (int it = 0; it < 256; ++it) {
      int k = it * 64 + lane;
      float wval = W[(size_t)o * 16384 + k];
      int f = k >> 7, p = k & 127;
#pragma unroll
      for (int bb = 0; bb < 16; ++bb)
        acc[bb] += wval * (x0_s[bb][f] * x_s[bb][p]);
    }
#pragma unroll
    for (int bb = 0; bb < 16; ++bb) {
      float v = acc[bb];
      for (int off = 32; off; off >>= 1) v += __shfl_down(v, off);
      if (lane == 0) out[(size_t)(b0 + bb) * 256 + o] = v + bias[o];
    }
  }
}

// ------------------------------- launcher ----------------------------------
extern "C" void kernel_launch(void* const* d_in, const int* in_sizes, int n_in,
                              void* d_out, int out_size, void* d_ws,
                              size_t ws_size, hipStream_t stream)
{
  const float* x0   = (const float*)d_in[0];
  const float* x    = (const float*)d_in[1];
  const float* W    = (const float*)d_in[2];
  const float* bias = (const float*)d_in[3];
  float* out = (float*)d_out;

  if (ws_size >= (size_t)WS_NEEDED) {
    _Float16* WT2  = (_Float16*)((char*)d_ws + WS_WT_OFF);
    _Float16* Xf   = (_Float16*)((char*)d_ws + WS_XF_OFF);
    _Float16* X0T2 = (_Float16*)((char*)d_ws + WS_X0_OFF);
    prep_kernel<<<2560, 256, 0, stream>>>(x0, x, W, WT2, Xf, X0T2);
    gemm_kernel<<<256, 512, 0, stream>>>(WT2, Xf, X0T2, bias, out);
  } else {
    naive_kernel<<<256, 256, 0, stream>>>(x0, x, W, bias, out);
  }
}